// Round 4
// baseline (259.456 us; speedup 1.0000x reference)
//
#include <hip/hip_runtime.h>

// Problem: Embedding_6940667150787
//   idx:      [131072] int32 in [0, 198)
//   wordlist: [198, 512] float32
//   out:      [131072, 512] float32 = wordlist[idx] + positional_encoding
//
// PE: for j in 0..254: angle = i / 10000^(2j/512);
//     pe[i, 2j] = sin(angle), pe[i, 2j+1] = cos(angle); cols 510,511 = 0.
//
// R6 = R5 resubmitted (round 3 failed on container infra, no data).
//   Diagnosis: kernel ~91us moving 268MB W + 268MB gather R = 536MB at
//   ~5.9 TB/s == HBM ceiling -> the write stream thrashes L2+L3 (268MB
//   written > 256MB L3), so wordlist re-reads fetch from HBM every time.
//   Fix: block owns an 8-float4 column slice (128B/row); its whole wordlist
//   working set = 198 x 128B = 25KB -> staged once in LDS (immune to write
//   thrash). Gathers become ds_read_b128. Global wordlist reads: 268MB->51MB.
//   Per-thread math (fixed col pair, rotation over 32 rows) unchanged.
//   tok-XOR granule swizzle breaks the same-bank pattern of random rows.

#define L_TOTAL 131072
#define DEPTH_F4 128      // float4 per row (512 floats)
#define R 32              // rows per thread (one row-group)
#define CCQ 8             // float4-cols per chunk (128B row slice)
#define NCHUNK 16         // 128 / CCQ
#define RG_PER_BLOCK 32   // row-groups per block (4 waves x 8 lane-groups)
#define VOCAB 198

typedef float f32x4 __attribute__((ext_vector_type(4)));
typedef int   i32x4 __attribute__((ext_vector_type(4)));

__device__ __forceinline__ void sincos_fast(float a, float& s, float& c) {
    // Cody-Waite reduction by 2*pi (FMA), then HW transcendental
    // (input in REVOLUTIONS).
    const float INV2PI = 0.15915493667125702f;
    const float PI2_HI = 6.2831854820251465f;
    const float PI2_LO = -1.7484555314695172e-7f;
    float k = rintf(a * INV2PI);               // exact in fp32 (k <= ~2.1e4)
    float r = fmaf(-k, PI2_HI, a);
    r = fmaf(-k, PI2_LO, r);                   // |r| <= pi, err ~4e-7 rad
    float rev = r * INV2PI;
    s = __builtin_amdgcn_sinf(rev);            // v_sin_f32: sin(rev*2pi)
    c = __builtin_amdgcn_cosf(rev);            // v_cos_f32
}

__global__ __launch_bounds__(256) void embed_pe_kernel(
    const int* __restrict__ idx,
    const float* __restrict__ wordlist,
    float* __restrict__ out)
{
    // 25,344 B: wordlist rows 0..197, this block's 8-float4 column slice.
    __shared__ f32x4 lds[VOCAB * CCQ];

    int tid   = threadIdx.x;
    int bid   = blockIdx.x;
    int chunk = bid >> 7;          // 0..15: which 8-float4 column slice
    int rgb   = bid & 127;         // 0..127: which group of 32 row-groups

    // ---- Stage wordlist slice into LDS (once per block) ----
    // tok-XOR swizzle on the 16B granule: row r, granule g stored at g^(r&7),
    // so random-row gathers spread across banks.
    for (int u = tid; u < VOCAB * CCQ; u += 256) {
        int r = u >> 3, g = u & 7;
        f32x4 v = ((const f32x4*)wordlist)[r * DEPTH_F4 + chunk * CCQ + g];
        lds[r * CCQ + (g ^ (r & 7))] = v;
    }
    __syncthreads();

    // ---- Lane -> (row-group, column) mapping ----
    int wave = tid >> 6;
    int lane = tid & 63;
    int rgl  = lane >> 3;          // 8 row-groups per wave
    int ccq  = lane & 7;           // 8 float4-cols per wave
    int rg   = rgb * RG_PER_BLOCK + wave * 8 + rgl;   // 0..4095
    int i0   = rg * R;             // first row of this thread's group
    int cc   = chunk * CCQ + ccq;  // float4 column 0..127

    // Inverse frequencies for pair j0=2cc (cols 4cc,4cc+1), j1=2cc+1.
    const float K = 0.051905126483205076f;     // log2(10000) / 256
    float invf0 = exp2f(-(float)(2 * cc)     * K);
    float invf1 = exp2f(-(float)(2 * cc + 1) * K);

    // Base-row sin/cos (full reduction) + per-row-step rotation.
    float s0, c0, s1, c1, sd0, cd0, sd1, cd1;
    sincos_fast((float)i0 * invf0, s0, c0);
    sincos_fast((float)i0 * invf1, s1, c1);
    sincos_fast(invf0, sd0, cd0);
    sincos_fast(invf1, sd1, cd1);

    // cols 510,511 must be PE=0; (0,0) is a fixed point of the rotation.
    if (cc == DEPTH_F4 - 1) { s1 = 0.0f; c1 = 0.0f; }

    const i32x4* ip = (const i32x4*)idx + rg * (R / 4);
    f32x4*       op = (f32x4*)out + (size_t)i0 * DEPTH_F4 + cc;

#pragma unroll
    for (int ch = 0; ch < R / 8; ++ch) {
        // Tokens for this chunk's 8 rows (uniform within each 8-lane group).
        i32x4 ta = ip[ch * 2];
        i32x4 tb = ip[ch * 2 + 1];
        int tok[8] = { ta[0], ta[1], ta[2], ta[3],
                       tb[0], tb[1], tb[2], tb[3] };

#pragma unroll
        for (int k = 0; k < 8; ++k) {
            int t = tok[k];
            f32x4 w = lds[t * CCQ + (ccq ^ (t & 7))];
            f32x4 o;
            o[0] = w[0] + s0;
            o[1] = w[1] + c0;
            o[2] = w[2] + s1;
            o[3] = w[3] + c1;
            op[(size_t)(ch * 8 + k) * DEPTH_F4] = o;

            // rotate angles forward by one row: (s,c) <- angle + invf
            float ns0 = fmaf(s0, cd0, c0 * sd0);
            float nc0 = fmaf(c0, cd0, -s0 * sd0);
            s0 = ns0; c0 = nc0;
            float ns1 = fmaf(s1, cd1, c1 * sd1);
            float nc1 = fmaf(c1, cd1, -s1 * sd1);
            s1 = ns1; c1 = nc1;
        }
    }
}

extern "C" void kernel_launch(void* const* d_in, const int* in_sizes, int n_in,
                              void* d_out, int out_size, void* d_ws, size_t ws_size,
                              hipStream_t stream) {
    const int*   idx      = (const int*)d_in[0];
    const float* wordlist = (const float*)d_in[1];
    float*       out      = (float*)d_out;

    // (131072/32 row-groups / 32 per block) x 16 column chunks = 2048 blocks
    int grid = (L_TOTAL / R / RG_PER_BLOCK) * NCHUNK;
    embed_pe_kernel<<<grid, 256, 0, stream>>>(idx, wordlist, out);
}

// Round 5
// 259.072 us; speedup vs baseline: 1.0015x; 1.0015x over previous
//
#include <hip/hip_runtime.h>

// Problem: Embedding_6940667150787
//   idx:      [131072] int32 in [0, 198)
//   wordlist: [198, 512] float32
//   out:      [131072, 512] float32 = wordlist[idx] + positional_encoding
//
// PE: for j in 0..254: angle = i / 10000^(2j/512);
//     pe[i, 2j] = sin(angle), pe[i, 2j+1] = cos(angle); cols 510,511 = 0.
//
// R7: pure-store main loop (vmcnt decoupling).
//   Evidence: R4 (global gather), R5 (LDS gather, global idx) identical at
//   ~92-97us = 2.9 TB/s writes, while fillBufferAligned sustains 6.6 TB/s at
//   10% occupancy. Theory: loads and stores share vmcnt; the per-chunk
//   global idx load's s_waitcnt vmcnt(N) drains the wave's store queue every
//   8 rows, collapsing outstanding-store depth (BW = bytes-in-flight / ack
//   latency). Fix: stage idx into LDS as well; main loop = ds_read (lgkmcnt)
//   + VALU + global_store (vmcnt) only -> store queue fills to HW depth.

#define L_TOTAL 131072
#define DEPTH_F4 128      // float4 per row (512 floats)
#define R 32              // rows per thread (one row-group)
#define CCQ 8             // float4-cols per chunk (128B row slice)
#define NCHUNK 16         // 128 / CCQ
#define RG_PER_BLOCK 32   // row-groups per block (4 waves x 8 lane-groups)
#define VOCAB 198

typedef float f32x4 __attribute__((ext_vector_type(4)));
typedef int   i32x4 __attribute__((ext_vector_type(4)));

__device__ __forceinline__ void sincos_fast(float a, float& s, float& c) {
    // Cody-Waite reduction by 2*pi (FMA), then HW transcendental
    // (input in REVOLUTIONS).
    const float INV2PI = 0.15915493667125702f;
    const float PI2_HI = 6.2831854820251465f;
    const float PI2_LO = -1.7484555314695172e-7f;
    float k = rintf(a * INV2PI);               // exact in fp32 (k <= ~2.1e4)
    float r = fmaf(-k, PI2_HI, a);
    r = fmaf(-k, PI2_LO, r);                   // |r| <= pi, err ~4e-7 rad
    float rev = r * INV2PI;
    s = __builtin_amdgcn_sinf(rev);            // v_sin_f32: sin(rev*2pi)
    c = __builtin_amdgcn_cosf(rev);            // v_cos_f32
}

__global__ __launch_bounds__(256) void embed_pe_kernel(
    const int* __restrict__ idx,
    const float* __restrict__ wordlist,
    float* __restrict__ out)
{
    // 25,344 B: wordlist rows 0..197, this block's 8-float4 column slice.
    __shared__ f32x4 wl_lds[VOCAB * CCQ];
    // 4 KB: this block's 1024 idx values (32 row-groups x 32 rows).
    __shared__ i32x4 idx_lds[RG_PER_BLOCK * R / 4];

    int tid   = threadIdx.x;
    int bid   = blockIdx.x;
    int chunk = bid >> 7;          // 0..15: which 8-float4 column slice
    int rgb   = bid & 127;         // 0..127: which group of 32 row-groups

    // ---- Stage wordlist slice into LDS (once per block) ----
    for (int u = tid; u < VOCAB * CCQ; u += 256) {
        int r = u >> 3, g = u & 7;
        f32x4 v = ((const f32x4*)wordlist)[r * DEPTH_F4 + chunk * CCQ + g];
        wl_lds[r * CCQ + (g ^ (r & 7))] = v;
    }
    // ---- Stage this block's 1024 idx values (one i32x4 per thread) ----
    idx_lds[tid] = ((const i32x4*)idx)[rgb * 256 + tid];
    __syncthreads();

    // ---- Lane -> (row-group, column) mapping ----
    int wave = tid >> 6;
    int lane = tid & 63;
    int rgl  = lane >> 3;          // 8 row-groups per wave
    int ccq  = lane & 7;           // 8 float4-cols per wave
    int lrg  = wave * 8 + rgl;     // local row-group 0..31
    int rg   = rgb * RG_PER_BLOCK + lrg;              // 0..4095
    int i0   = rg * R;             // first row of this thread's group
    int cc   = chunk * CCQ + ccq;  // float4 column 0..127

    // Inverse frequencies for pair j0=2cc (cols 4cc,4cc+1), j1=2cc+1.
    const float K = 0.051905126483205076f;     // log2(10000) / 256
    float invf0 = exp2f(-(float)(2 * cc)     * K);
    float invf1 = exp2f(-(float)(2 * cc + 1) * K);

    // Base-row sin/cos (full reduction) + per-row-step rotation.
    float s0, c0, s1, c1, sd0, cd0, sd1, cd1;
    sincos_fast((float)i0 * invf0, s0, c0);
    sincos_fast((float)i0 * invf1, s1, c1);
    sincos_fast(invf0, sd0, cd0);
    sincos_fast(invf1, sd1, cd1);

    // cols 510,511 must be PE=0; (0,0) is a fixed point of the rotation.
    if (cc == DEPTH_F4 - 1) { s1 = 0.0f; c1 = 0.0f; }

    f32x4* op = (f32x4*)out + (size_t)i0 * DEPTH_F4 + cc;

    // Main loop: ds_read (lgkmcnt) + VALU + global_store (vmcnt) ONLY.
    // No vmem loads -> no vmcnt waits -> store queue stays deep.
#pragma unroll
    for (int ch = 0; ch < R / 8; ++ch) {
        // Tokens for this chunk's 8 rows (uniform within each 8-lane group).
        i32x4 ta = idx_lds[lrg * 8 + ch * 2];
        i32x4 tb = idx_lds[lrg * 8 + ch * 2 + 1];
        int tok[8] = { ta[0], ta[1], ta[2], ta[3],
                       tb[0], tb[1], tb[2], tb[3] };

#pragma unroll
        for (int k = 0; k < 8; ++k) {
            int t = tok[k];
            f32x4 w = wl_lds[t * CCQ + (ccq ^ (t & 7))];
            f32x4 o;
            o[0] = w[0] + s0;
            o[1] = w[1] + c0;
            o[2] = w[2] + s1;
            o[3] = w[3] + c1;
            op[(size_t)(ch * 8 + k) * DEPTH_F4] = o;

            // rotate angles forward by one row: (s,c) <- angle + invf
            float ns0 = fmaf(s0, cd0, c0 * sd0);
            float nc0 = fmaf(c0, cd0, -s0 * sd0);
            s0 = ns0; c0 = nc0;
            float ns1 = fmaf(s1, cd1, c1 * sd1);
            float nc1 = fmaf(c1, cd1, -s1 * sd1);
            s1 = ns1; c1 = nc1;
        }
    }
}

extern "C" void kernel_launch(void* const* d_in, const int* in_sizes, int n_in,
                              void* d_out, int out_size, void* d_ws, size_t ws_size,
                              hipStream_t stream) {
    const int*   idx      = (const int*)d_in[0];
    const float* wordlist = (const float*)d_in[1];
    float*       out      = (float*)d_out;

    // (131072/32 row-groups / 32 per block) x 16 column chunks = 2048 blocks
    int grid = (L_TOTAL / R / RG_PER_BLOCK) * NCHUNK;
    embed_pe_kernel<<<grid, 256, 0, stream>>>(idx, wordlist, out);
}